// Round 13
// baseline (385.221 us; speedup 1.0000x reference)
//
#include <hip/hip_runtime.h>
#include <hip/hip_bf16.h>
#include <stdint.h>

#define B_   32
#define S_   577
#define SP   640
#define D_   1024
#define H_   16
#define DH   64
#define BH_  (B_*H_)
#define M_   (B_*S_)      // 18464
#define MP2  18688        // padded to 256
#define SCALE_ 0.125f
#define LOG2E_ 1.44269504088896f

typedef __bf16 bf16;
typedef __bf16 bf16x8 __attribute__((ext_vector_type(8)));
typedef __bf16 bf16x4 __attribute__((ext_vector_type(4)));
typedef float  f32x4  __attribute__((ext_vector_type(4)));

#define BARRIER() __builtin_amdgcn_s_barrier()

template<int N> __device__ __forceinline__ void vmwait() {
    if constexpr (N == 8) asm volatile("s_waitcnt vmcnt(8)" ::: "memory");
    else if constexpr (N == 4) asm volatile("s_waitcnt vmcnt(4)" ::: "memory");
    else if constexpr (N == 0) asm volatile("s_waitcnt vmcnt(0)" ::: "memory");
    // N < 0: no wait
}

__device__ __forceinline__ void gload16(const bf16* g, bf16* l) {
    __builtin_amdgcn_global_load_lds((__attribute__((address_space(1))) void*)g,
                                     (__attribute__((address_space(3))) void*)l, 16, 0, 0);
}

// ---------------- cast fp32 -> bf16 ----------------
__global__ void cast_kernel(const float* __restrict__ in, bf16* __restrict__ out, int n4) {
    int i = blockIdx.x * blockDim.x + threadIdx.x;
    if (i >= n4) return;
    float4 v = ((const float4*)in)[i];
    bf16x4 o;
    o[0] = (bf16)v.x; o[1] = (bf16)v.y; o[2] = (bf16)v.z; o[3] = (bf16)v.w;
    ((bf16x4*)out)[i] = o;
}

__global__ void cast4_kernel(const float* __restrict__ w0, const float* __restrict__ w1,
                             const float* __restrict__ w2, const float* __restrict__ w3,
                             bf16* __restrict__ o0, bf16* __restrict__ o1,
                             bf16* __restrict__ o2, bf16* __restrict__ o3) {
    int i = blockIdx.x * blockDim.x + threadIdx.x;
    int seg = i >> 18, r = i & 262143;
    const float* in = (seg == 0) ? w0 : (seg == 1) ? w1 : (seg == 2) ? w2 : w3;
    bf16* out       = (seg == 0) ? o0 : (seg == 1) ? o1 : (seg == 2) ? o2 : o3;
    float4 v = ((const float4*)in)[r];
    bf16x4 o;
    o[0] = (bf16)v.x; o[1] = (bf16)v.y; o[2] = (bf16)v.z; o[3] = (bf16)v.w;
    ((bf16x4*)out)[r] = o;
}

// =============== 256x256 tile, BK=32, phase-interleaved pipelined GEMM ===============
// 4 circular K-tile buffers x 32 KB (A 16 + B 16) = 128 KB. Stage kt+3 during kt's
// phases (A-half in phase A, B-half in phase B; 2 gload16 each). Each K-tile = 2
// phases of 16 MFMA with per-phase {ds_read || stage || bar || lgkm0 || setprio MFMA || bar}.
// vmcnt(8) once per K-tile (phase B): own-wave count + barrier => kt+1 fully in LDS,
// kt+2/kt+3's 8 loads STAY IN FLIGHT (never drains in steady state).
// WAR: stage target (kt+3)&3 == (kt-1)&3, freed by kt-1's trailing barrier (all
// waves' ds_reads retired in-order before their MFMA). LDS layout = R11-verified
// packed BK=32 XOR involution.
__device__ __forceinline__ void stageA3(const bf16* __restrict__ A, int m0, int kt,
                                        bf16* nxt, int tid, int wave) {
    #pragma unroll
    for (int ld = 0; ld < 2; ++ld) {
        int ci = ld * 512 + tid, lr = ci >> 3, ch = (ci & 7) ^ (lr & 7);
        int row = lr * 2 + (ch >> 2), kof = (ch & 3) * 8;
        gload16(A + (size_t)(m0 + row) * 1024 + kt * 32 + kof,
                nxt + (size_t)(ld * 512 + wave * 64) * 8);
    }
}
__device__ __forceinline__ void stageB3(const bf16* __restrict__ Bw, int n0, int kt,
                                        bf16* nxt, int tid, int wave) {
    #pragma unroll
    for (int ld = 0; ld < 2; ++ld) {
        int ci = ld * 512 + tid, lr = ci >> 3, ch = (ci & 7) ^ (lr & 7);
        int row = lr * 2 + (ch >> 2), kof = (ch & 3) * 8;
        gload16(Bw + (size_t)(n0 + row) * 1024 + kt * 32 + kof,
                nxt + 8192 + (size_t)(ld * 512 + wave * 64) * 8);
    }
}

template<int VMN, bool STG>
__device__ __forceinline__ void ktile(const bf16* __restrict__ A, const bf16* __restrict__ Bw,
                                      int m0, int n0, int kt, bf16* SM, f32x4 acc[8][4],
                                      int wm, int wn, int r16, int c4, int tid, int wave) {
    bf16* cur = SM + (kt & 3) * 16384;
    bf16* nxt = SM + ((kt + 3) & 3) * 16384;
    bf16x8 af[4], bfr[4];

    // ---------- phase A: m-lo x all-n ----------
    #pragma unroll
    for (int i = 0; i < 4; ++i) {
        int row = wm * 128 + i * 16 + r16, lr = row >> 1;
        int cc = (((row & 1) << 2) + c4) ^ (lr & 7);
        af[i] = *(const bf16x8*)(cur + lr * 64 + cc * 8);
    }
    #pragma unroll
    for (int j = 0; j < 4; ++j) {
        int row = wn * 64 + j * 16 + r16, lr = row >> 1;
        int cc = (((row & 1) << 2) + c4) ^ (lr & 7);
        bfr[j] = *(const bf16x8*)(cur + 8192 + lr * 64 + cc * 8);
    }
    if (STG) stageA3(A, m0, kt + 3, nxt, tid, wave);
    BARRIER();
    asm volatile("s_waitcnt lgkmcnt(0)" ::: "memory");
    __builtin_amdgcn_s_setprio(1);
    #pragma unroll
    for (int i = 0; i < 4; ++i)
        #pragma unroll
        for (int j = 0; j < 4; ++j)
            acc[i][j] = __builtin_amdgcn_mfma_f32_16x16x32_bf16(af[i], bfr[j], acc[i][j], 0, 0, 0);
    __builtin_amdgcn_s_setprio(0);
    BARRIER();

    // ---------- phase B: m-hi x all-n (B-frags reused from registers) ----------
    #pragma unroll
    for (int i = 0; i < 4; ++i) {
        int row = wm * 128 + (4 + i) * 16 + r16, lr = row >> 1;
        int cc = (((row & 1) << 2) + c4) ^ (lr & 7);
        af[i] = *(const bf16x8*)(cur + lr * 64 + cc * 8);
    }
    if (STG) stageB3(Bw, n0, kt + 3, nxt, tid, wave);
    vmwait<VMN>();                 // guards kt+1 (after barrier below)
    BARRIER();
    asm volatile("s_waitcnt lgkmcnt(0)" ::: "memory");
    __builtin_amdgcn_s_setprio(1);
    #pragma unroll
    for (int i = 0; i < 4; ++i)
        #pragma unroll
        for (int j = 0; j < 4; ++j)
            acc[4 + i][j] = __builtin_amdgcn_mfma_f32_16x16x32_bf16(af[i], bfr[j], acc[4 + i][j], 0, 0, 0);
    __builtin_amdgcn_s_setprio(0);
    BARRIER();
}

__device__ __forceinline__ void gemm_mainloop(const bf16* __restrict__ A, const bf16* __restrict__ Bw,
                                              int m0, int n0, bf16* SM, f32x4 acc[8][4],
                                              int wm, int wn, int r16, int c4, int tid, int wave) {
    // prologue: stage K-tiles 0,1,2 (A then B each -> oldest 4 loads = tile 0)
    #pragma unroll
    for (int kt = 0; kt < 3; ++kt) {
        bf16* buf = SM + kt * 16384;
        stageA3(A, m0, kt, buf, tid, wave);
        stageB3(Bw, n0, kt, buf, tid, wave);
    }
    vmwait<8>();                   // retire tile 0's 4 loads; tiles 1,2 in flight
    BARRIER();
    for (int kt = 0; kt < 29; ++kt)
        ktile<8, true>(A, Bw, m0, n0, kt, SM, acc, wm, wn, r16, c4, tid, wave);
    ktile<4, false>(A, Bw, m0, n0, 29, SM, acc, wm, wn, r16, c4, tid, wave);
    ktile<0, false>(A, Bw, m0, n0, 30, SM, acc, wm, wn, r16, c4, tid, wave);
    ktile<-1, false>(A, Bw, m0, n0, 31, SM, acc, wm, wn, r16, c4, tid, wave);
}

// ---------------- QKV projection: [MP2,1024] x [3072,1024]^T ----------------
__global__ __launch_bounds__(512, 2) void gemm_qkv(const bf16* __restrict__ A, const bf16* __restrict__ Bw,
                                                   const float* __restrict__ qb, const float* __restrict__ kb,
                                                   const float* __restrict__ vb,
                                                   bf16* __restrict__ qk, bf16* __restrict__ vT) {
    __shared__ __align__(16) char SMc[131072];     // 4 x 32 KB; Ts 128x259 bf16 fits
    bf16* SM = (bf16*)SMc;
    const int bx = blockIdx.x;
    const int bm = bx / 12, bn = bx % 12;
    const int m0 = bm * 256, n0 = bn * 256;
    const int tid = threadIdx.x;
    const int lane = tid & 63, wave = tid >> 6;
    const int wm = wave >> 2, wn = wave & 3;
    const int r16 = lane & 15, c4 = lane >> 4;

    f32x4 acc[8][4];
    #pragma unroll
    for (int i = 0; i < 8; ++i)
        #pragma unroll
        for (int j = 0; j < 4; ++j)
            #pragma unroll
            for (int r = 0; r < 4; ++r) acc[i][j][r] = 0.0f;

    gemm_mainloop(A, Bw, m0, n0, SM, acc, wm, wn, r16, c4, tid, wave);
    __syncthreads();   // full drain before epilogue / SM reuse

    if (bn < 8) {
        const float* barr = (bn < 4) ? qb : kb;
        const float mul = (bn < 4) ? SCALE_ * LOG2E_ : 1.0f;
        #pragma unroll
        for (int j = 0; j < 4; ++j) {
            int n = n0 + wn * 64 + j * 16 + r16;
            float bias = barr[n & 1023];
            #pragma unroll
            for (int i = 0; i < 8; ++i) {
                #pragma unroll
                for (int r = 0; r < 4; ++r) {
                    int m = m0 + wm * 128 + i * 16 + c4 * 4 + r;
                    if (m < M_) qk[(size_t)m * 2048 + n] = (bf16)((acc[i][j][r] + bias) * mul);
                }
            }
        }
    } else {
        const int bnp = bn - 8;
        bf16* Ts = (bf16*)SMc;                      // [128][259]
        #pragma unroll
        for (int mh = 0; mh < 2; ++mh) {
            if (wm == mh) {
                #pragma unroll
                for (int j = 0; j < 4; ++j) {
                    int nl = wn * 64 + j * 16 + r16;
                    float bias = vb[bnp * 256 + nl];
                    #pragma unroll
                    for (int i = 0; i < 8; ++i) {
                        #pragma unroll
                        for (int r = 0; r < 4; ++r) {
                            int tr = i * 16 + c4 * 4 + r;
                            Ts[tr * 259 + nl] = (bf16)(acc[i][j][r] + bias);
                        }
                    }
                }
            }
            __syncthreads();
            {
                int ml = tid & 127, nh = tid >> 7;
                int gm = m0 + mh * 128 + ml;
                if (gm < M_) {
                    unsigned bb = (unsigned)gm / 577u, s = (unsigned)gm - bb * 577u;
                    bf16* dst = vT + ((size_t)((bb * 16 + bnp * 4 + nh) * 64)) * SP + s;
                    const bf16* src = Ts + ml * 259 + nh * 64;
                    #pragma unroll 8
                    for (int j = 0; j < 64; ++j) dst[(size_t)j * SP] = src[j];
                }
            }
            __syncthreads();
        }
    }
}

// ---------------- output projection: [MP2,1024] x [1024,1024]^T + bias -> fp32 ----------------
__global__ __launch_bounds__(512, 2) void gemm_out(const bf16* __restrict__ A, const bf16* __restrict__ Bw,
                                                   const float* __restrict__ ob, float* __restrict__ out) {
    __shared__ __align__(16) bf16 SM[4 * 16384];   // 128 KB
    const int bx = blockIdx.x;
    const int bm = bx >> 2, bn = bx & 3;
    const int m0 = bm * 256, n0 = bn * 256;
    const int tid = threadIdx.x;
    const int lane = tid & 63, wave = tid >> 6;
    const int wm = wave >> 2, wn = wave & 3;
    const int r16 = lane & 15, c4 = lane >> 4;

    f32x4 acc[8][4];
    #pragma unroll
    for (int i = 0; i < 8; ++i)
        #pragma unroll
        for (int j = 0; j < 4; ++j)
            #pragma unroll
            for (int r = 0; r < 4; ++r) acc[i][j][r] = 0.0f;

    gemm_mainloop(A, Bw, m0, n0, SM, acc, wm, wn, r16, c4, tid, wave);

    #pragma unroll
    for (int j = 0; j < 4; ++j) {
        int n = n0 + wn * 64 + j * 16 + r16;
        float bias = ob[n];
        #pragma unroll
        for (int i = 0; i < 8; ++i) {
            #pragma unroll
            for (int r = 0; r < 4; ++r) {
                int m = m0 + wm * 128 + i * 16 + c4 * 4 + r;
                if (m < M_) out[(size_t)m * 1024 + n] = acc[i][j][r] + bias;
            }
        }
    }
}

// ---------------- flash attention (R8 verbatim: LDS K/V staging, __syncthreads) ----------------
__global__ __launch_bounds__(256) void attn_kernel(const bf16* __restrict__ qk,
                                                   const bf16* __restrict__ vT, bf16* __restrict__ obuf) {
    __shared__ __align__(16) bf16 KV[2][2][4096];      // [buf][K|V][64x64] = 32 KB
    __shared__ __align__(16) char Pls[4 * 2 * 2048];   // 16 KB
    const int orig = blockIdx.x;
    const int xcd = orig & 7;
    const int t   = orig >> 3;
    const int qt  = t % 5, bhg = t / 5;
    const int bh  = bhg * 8 + xcd;
    const int b   = bh >> 4, h = bh & 15;
    const int tid = threadIdx.x;
    const int lane = tid & 63, wave = tid >> 6;
    const int r16 = lane & 15, c4 = lane >> 4;
    const int q0  = qt * 128 + wave * 32;
    const int swz = (r16 & 7) << 4;

    const bf16* qp = qk + (size_t)(b * 577) * 2048 + h * 64;
    const bf16* kp = qp + 1024;
    const bf16* vp = vT + (size_t)bh * 64 * SP;

    bf16x8 aq[2][2];
    #pragma unroll
    for (int qf = 0; qf < 2; ++qf)
        #pragma unroll
        for (int c = 0; c < 2; ++c)
            aq[qf][c] = *(const bf16x8*)(qp + (size_t)(q0 + qf * 16 + r16) * 2048 + c * 32 + c4 * 8);

    float mi[2] = {-3.0e38f, -3.0e38f};
    float li[2] = {0.0f, 0.0f};
    f32x4 accO[2][4];
    #pragma unroll
    for (int qf = 0; qf < 2; ++qf)
        #pragma unroll
        for (int nt = 0; nt < 4; ++nt)
            #pragma unroll
            for (int r = 0; r < 4; ++r) accO[qf][nt][r] = 0.0f;

    char* pbase = Pls + wave * 4096 + r16 * 128;

    auto stageKV = [&](int kt, int buf) {
        #pragma unroll
        for (int half = 0; half < 2; ++half) {
            int li  = half * 256 + tid;
            int row = li >> 3;
            int ch  = (li & 7) ^ (row & 7);
            bf16* lk = &KV[buf][0][(size_t)(half * 256 + wave * 64) * 8];
            bf16* lv = &KV[buf][1][(size_t)(half * 256 + wave * 64) * 8];
            gload16(kp + (size_t)(kt * 64 + row) * 2048 + ch * 8, lk);
            gload16(vp + (size_t)row * SP + kt * 64 + ch * 8, lv);
        }
    };

    stageKV(0, 0);
    __syncthreads();

    for (int kt = 0; kt < 10; ++kt) {
        const int buf = kt & 1;
        if (kt < 9) stageKV(kt + 1, buf ^ 1);

        bf16x8 kf[4][2];
        #pragma unroll
        for (int nt = 0; nt < 4; ++nt)
            #pragma unroll
            for (int c = 0; c < 2; ++c) {
                int row = nt * 16 + r16;
                int cc  = (c * 4 + c4) ^ (row & 7);
                kf[nt][c] = *(const bf16x8*)(&KV[buf][0][row * 64 + cc * 8]);
            }
        f32x4 sc[2][4];
        #pragma unroll
        for (int qf = 0; qf < 2; ++qf)
            #pragma unroll
            for (int nt = 0; nt < 4; ++nt) {
                f32x4 z = {0.0f, 0.0f, 0.0f, 0.0f};
                z = __builtin_amdgcn_mfma_f32_16x16x32_bf16(kf[nt][0], aq[qf][0], z, 0, 0, 0);
                sc[qf][nt] = __builtin_amdgcn_mfma_f32_16x16x32_bf16(kf[nt][1], aq[qf][1], z, 0, 0, 0);
            }

        #pragma unroll
        for (int qf = 0; qf < 2; ++qf) {
            if (kt == 9) {
                #pragma unroll
                for (int nt = 0; nt < 4; ++nt)
                    #pragma unroll
                    for (int r = 0; r < 4; ++r)
                        if (576 + nt * 16 + c4 * 4 + r >= S_) sc[qf][nt][r] = -3.0e38f;
            }
            float pmax = sc[qf][0][0];
            #pragma unroll
            for (int nt = 0; nt < 4; ++nt)
                #pragma unroll
                for (int r = 0; r < 4; ++r) pmax = fmaxf(pmax, sc[qf][nt][r]);
            pmax = fmaxf(pmax, __shfl_xor(pmax, 16));
            pmax = fmaxf(pmax, __shfl_xor(pmax, 32));

            const bool vrow = (q0 + qf * 16 + r16) < S_;
            int ok = (!vrow) || (pmax <= mi[qf] + 8.0f);
            if (!__all(ok)) {
                float mnew = fmaxf(mi[qf], pmax);
                float fsc  = __builtin_amdgcn_exp2f(mi[qf] - mnew);
                mi[qf] = mnew;
                li[qf] *= fsc;
                float fs0 = __shfl(fsc, c4 * 4 + 0);
                float fs1 = __shfl(fsc, c4 * 4 + 1);
                float fs2 = __shfl(fsc, c4 * 4 + 2);
                float fs3 = __shfl(fsc, c4 * 4 + 3);
                #pragma unroll
                for (int nt = 0; nt < 4; ++nt) {
                    accO[qf][nt][0] *= fs0; accO[qf][nt][1] *= fs1;
                    accO[qf][nt][2] *= fs2; accO[qf][nt][3] *= fs3;
                }
            }
            float p[4][4];
            float rs = 0.0f;
            #pragma unroll
            for (int nt = 0; nt < 4; ++nt)
                #pragma unroll
                for (int r = 0; r < 4; ++r) {
                    p[nt][r] = __builtin_amdgcn_exp2f(sc[qf][nt][r] - mi[qf]);
                    rs += p[nt][r];
                }
            rs += __shfl_xor(rs, 16);
            rs += __shfl_xor(rs, 32);
            li[qf] += rs;
            #pragma unroll
            for (int nt = 0; nt < 4; ++nt) {
                bf16x4 pk;
                pk[0] = (bf16)p[nt][0]; pk[1] = (bf16)p[nt][1];
                pk[2] = (bf16)p[nt][2]; pk[3] = (bf16)p[nt][3];
                *(bf16x4*)(pbase + qf * 2048 + ((nt * 32 + c4 * 8) ^ swz)) = pk;
            }
        }

        bf16x8 vf[4][2];
        #pragma unroll
        for (int ntd = 0; ntd < 4; ++ntd)
            #pragma unroll
            for (int kk = 0; kk < 2; ++kk) {
                int row = ntd * 16 + r16;
                int cc  = (kk * 4 + c4) ^ (row & 7);
                vf[ntd][kk] = *(const bf16x8*)(&KV[buf][1][row * 64 + cc * 8]);
            }
        #pragma unroll
        for (int qf = 0; qf < 2; ++qf) {
            bf16x8 pf[2];
            #pragma unroll
            for (int kk = 0; kk < 2; ++kk)
                pf[kk] = *(const bf16x8*)(pbase + qf * 2048 + ((kk * 64 + c4 * 16) ^ swz));
            #pragma unroll
            for (int ntd = 0; ntd < 4; ++ntd)
                #pragma unroll
                for (int kk = 0; kk < 2; ++kk)
                    accO[qf][ntd] = __builtin_amdgcn_mfma_f32_16x16x32_bf16(pf[kk], vf[ntd][kk], accO[qf][ntd], 0, 0, 0);
        }

        __syncthreads();
    }

    #pragma unroll
    for (int qf = 0; qf < 2; ++qf) {
        float inv = 1.0f / li[qf];
        float rl0 = __shfl(inv, c4 * 4 + 0);
        float rl1 = __shfl(inv, c4 * 4 + 1);
        float rl2 = __shfl(inv, c4 * 4 + 2);
        float rl3 = __shfl(inv, c4 * 4 + 3);
        #pragma unroll
        for (int ntd = 0; ntd < 4; ++ntd) {
            #pragma unroll
            for (int r = 0; r < 4; ++r) {
                int s = q0 + qf * 16 + c4 * 4 + r;
                if (s < S_) {
                    float rl = (r == 0) ? rl0 : (r == 1) ? rl1 : (r == 2) ? rl2 : rl3;
                    obuf[((size_t)(b * S_ + s)) * 1024 + h * 64 + ntd * 16 + r16] =
                        (bf16)(accO[qf][ntd][r] * rl);
                }
            }
        }
    }
}

extern "C" void kernel_launch(void* const* d_in, const int* in_sizes, int n_in,
                              void* d_out, int out_size, void* d_ws, size_t ws_size,
                              hipStream_t stream) {
    const float* hs = (const float*)d_in[0];
    const float* qw = (const float*)d_in[1];
    const float* qb = (const float*)d_in[2];
    const float* kw = (const float*)d_in[3];
    const float* kb = (const float*)d_in[4];
    const float* vw = (const float*)d_in[5];
    const float* vb = (const float*)d_in[6];
    const float* ow = (const float*)d_in[7];
    const float* ob = (const float*)d_in[8];

    char* ws = (char*)d_ws;
    size_t off = 0;
    auto alloc = [&](size_t bytes) { void* p = ws + off; off += (bytes + 255) & ~255UL; return p; };
    bf16* hsA  = (bf16*)alloc((size_t)MP2 * 1024 * 2);
    bf16* wqkv = (bf16*)alloc((size_t)3072 * 1024 * 2);
    bf16* wo   = (bf16*)alloc((size_t)1024 * 1024 * 2);
    bf16* qk   = (bf16*)alloc((size_t)MP2 * 2048 * 2);
    bf16* vT   = (bf16*)alloc((size_t)BH_ * 64 * SP * 2);

    hipMemsetAsync(vT, 0, (size_t)BH_ * 64 * SP * 2, stream);

    int n4h = M_ * 1024 / 4;
    cast_kernel<<<(n4h + 255) / 256, 256, 0, stream>>>(hs, hsA, n4h);
    cast4_kernel<<<4096, 256, 0, stream>>>(qw, kw, vw, ow,
                                           wqkv, wqkv + 1048576, wqkv + 2097152, wo);

    gemm_qkv<<<73 * 12, 512, 0, stream>>>(hsA, wqkv, qb, kb, vb, qk, vT);
    attn_kernel<<<2560, 256, 0, stream>>>(qk, vT, hsA);
    gemm_out<<<73 * 4, 512, 0, stream>>>(hsA, wo, ob, (float*)d_out);
}

// Round 14
// 369.226 us; speedup vs baseline: 1.0433x; 1.0433x over previous
//
#include <hip/hip_runtime.h>
#include <hip/hip_bf16.h>
#include <stdint.h>

#define B_   32
#define S_   577
#define SP   640
#define D_   1024
#define H_   16
#define DH   64
#define BH_  (B_*H_)
#define M_   (B_*S_)      // 18464
#define MP2  18688        // padded to 256
#define SCALE_ 0.125f
#define LOG2E_ 1.44269504088896f

typedef __bf16 bf16;
typedef __bf16 bf16x8 __attribute__((ext_vector_type(8)));
typedef __bf16 bf16x4 __attribute__((ext_vector_type(4)));
typedef float  f32x4  __attribute__((ext_vector_type(4)));

__device__ __forceinline__ void gload16(const bf16* g, bf16* l) {
    __builtin_amdgcn_global_load_lds((__attribute__((address_space(1))) void*)g,
                                     (__attribute__((address_space(3))) void*)l, 16, 0, 0);
}

// ---------------- cast fp32 -> bf16 ----------------
__global__ void cast_kernel(const float* __restrict__ in, bf16* __restrict__ out, int n4) {
    int i = blockIdx.x * blockDim.x + threadIdx.x;
    if (i >= n4) return;
    float4 v = ((const float4*)in)[i];
    bf16x4 o;
    o[0] = (bf16)v.x; o[1] = (bf16)v.y; o[2] = (bf16)v.z; o[3] = (bf16)v.w;
    ((bf16x4*)out)[i] = o;
}

__global__ void cast4_kernel(const float* __restrict__ w0, const float* __restrict__ w1,
                             const float* __restrict__ w2, const float* __restrict__ w3,
                             bf16* __restrict__ o0, bf16* __restrict__ o1,
                             bf16* __restrict__ o2, bf16* __restrict__ o3) {
    int i = blockIdx.x * blockDim.x + threadIdx.x;
    int seg = i >> 18, r = i & 262143;
    const float* in = (seg == 0) ? w0 : (seg == 1) ? w1 : (seg == 2) ? w2 : w3;
    bf16* out       = (seg == 0) ? o0 : (seg == 1) ? o1 : (seg == 2) ? o2 : o3;
    float4 v = ((const float4*)in)[r];
    bf16x4 o;
    o[0] = (bf16)v.x; o[1] = (bf16)v.y; o[2] = (bf16)v.z; o[3] = (bf16)v.w;
    ((bf16x4*)out)[r] = o;
}

// ---------------- 256x256 tile, BK=64, double-buffered 2-phase GEMM core (R8, best) ----------------
__device__ __forceinline__ void stage256(const bf16* __restrict__ A, const bf16* __restrict__ B,
                                         int m0, int n0, int K, int kt, bf16* SMbuf) {
    const int tid = threadIdx.x;
    const int wave = tid >> 6;
    #pragma unroll
    for (int ld = 0; ld < 8; ++ld) {
        int li  = ld * 512 + tid;
        int row = (li >> 3) & 255;
        int ch  = (li & 7) ^ (row & 7);
        const bf16* g = ((ld < 4) ? (A + (size_t)(m0 + row) * K)
                                  : (B + (size_t)(n0 + row) * K)) + kt * 64 + ch * 8;
        bf16* l = SMbuf + (size_t)(ld * 512 + wave * 64) * 8;
        gload16(g, l);
    }
}

__device__ __forceinline__ void compute256(const bf16* SMbuf, f32x4 acc[8][4],
                                           int wm, int wn, int r16, int c4) {
    #pragma unroll
    for (int kk = 0; kk < 2; ++kk) {
        bf16x8 bq[4];
        #pragma unroll
        for (int j = 0; j < 4; ++j) {
            int row = wn * 64 + j * 16 + r16;
            int c   = (kk * 4 + c4) ^ (row & 7);
            bq[j] = *(const bf16x8*)(SMbuf + 16384 + row * 64 + c * 8);
        }
        #pragma unroll
        for (int i = 0; i < 8; ++i) {
            int row = wm * 128 + i * 16 + r16;
            int c   = (kk * 4 + c4) ^ (row & 7);
            bf16x8 a = *(const bf16x8*)(SMbuf + row * 64 + c * 8);
            #pragma unroll
            for (int j = 0; j < 4; ++j)
                acc[i][j] = __builtin_amdgcn_mfma_f32_16x16x32_bf16(a, bq[j], acc[i][j], 0, 0, 0);
        }
    }
}

// ---------------- QKV projection: [MP2,1024] x [3072,1024]^T (R8 verbatim) ----------------
__global__ __launch_bounds__(512, 2) void gemm_qkv(const bf16* __restrict__ A, const bf16* __restrict__ Bw,
                                                   const float* __restrict__ qb, const float* __restrict__ kb,
                                                   const float* __restrict__ vb,
                                                   bf16* __restrict__ qk, bf16* __restrict__ vT) {
    __shared__ __align__(16) bf16 SM[2 * 32768];   // 128 KB
    const int bx = blockIdx.x;
    const int bm = bx / 12, bn = bx % 12;
    const int m0 = bm * 256, n0 = bn * 256;
    const int tid = threadIdx.x;
    const int lane = tid & 63, wave = tid >> 6;
    const int wm = wave >> 2, wn = wave & 3;
    const int r16 = lane & 15, c4 = lane >> 4;

    f32x4 acc[8][4];
    #pragma unroll
    for (int i = 0; i < 8; ++i)
        #pragma unroll
        for (int j = 0; j < 4; ++j)
            #pragma unroll
            for (int r = 0; r < 4; ++r) acc[i][j][r] = 0.0f;

    stage256(A, Bw, m0, n0, 1024, 0, SM);
    __syncthreads();
    for (int kt = 0; kt < 16; ++kt) {
        if (kt < 15) stage256(A, Bw, m0, n0, 1024, kt + 1, SM + ((kt + 1) & 1) * 32768);
        compute256(SM + (kt & 1) * 32768, acc, wm, wn, r16, c4);
        __syncthreads();
    }

    if (bn < 8) {
        // Q (scale*log2e-prescaled) or K: direct stores into qk[M][2048]
        const float* barr = (bn < 4) ? qb : kb;
        const float mul = (bn < 4) ? SCALE_ * LOG2E_ : 1.0f;
        #pragma unroll
        for (int j = 0; j < 4; ++j) {
            int n = n0 + wn * 64 + j * 16 + r16;
            float bias = barr[n & 1023];
            #pragma unroll
            for (int i = 0; i < 8; ++i) {
                #pragma unroll
                for (int r = 0; r < 4; ++r) {
                    int m = m0 + wm * 128 + i * 16 + c4 * 4 + r;
                    if (m < M_) qk[(size_t)m * 2048 + n] = (bf16)((acc[i][j][r] + bias) * mul);
                }
            }
        }
    } else {
        // V: bounce through LDS, coalesced store along s into vT
        const int bnp = bn - 8;
        bf16* Ts = SM;                              // [128][259]
        #pragma unroll
        for (int mh = 0; mh < 2; ++mh) {
            if (wm == mh) {
                #pragma unroll
                for (int j = 0; j < 4; ++j) {
                    int nl = wn * 64 + j * 16 + r16;
                    float bias = vb[bnp * 256 + nl];
                    #pragma unroll
                    for (int i = 0; i < 8; ++i) {
                        #pragma unroll
                        for (int r = 0; r < 4; ++r) {
                            int tr = i * 16 + c4 * 4 + r;
                            Ts[tr * 259 + nl] = (bf16)(acc[i][j][r] + bias);
                        }
                    }
                }
            }
            __syncthreads();
            {
                int ml = tid & 127, nh = tid >> 7;
                int gm = m0 + mh * 128 + ml;
                if (gm < M_) {
                    unsigned bb = (unsigned)gm / 577u, s = (unsigned)gm - bb * 577u;
                    bf16* dst = vT + ((size_t)((bb * 16 + bnp * 4 + nh) * 64)) * SP + s;
                    const bf16* src = Ts + ml * 259 + nh * 64;
                    #pragma unroll 8
                    for (int j = 0; j < 64; ++j) dst[(size_t)j * SP] = src[j];
                }
            }
            __syncthreads();
        }
    }
}

// ---------------- output projection: 128x256 tile (tail fix: 580 blocks vs 292) ----------------
__device__ __forceinline__ void stage_out(const bf16* __restrict__ A, const bf16* __restrict__ B,
                                          int m0, int n0, int kt, bf16* SMbuf) {
    const int tid = threadIdx.x;
    const int wave = tid >> 6;
    #pragma unroll
    for (int ld = 0; ld < 2; ++ld) {                 // A: 128 rows x 8 chunks = 1024
        int li  = ld * 512 + tid;
        int row = li >> 3;
        int ch  = (li & 7) ^ (row & 7);
        gload16(A + (size_t)(m0 + row) * 1024 + kt * 64 + ch * 8,
                SMbuf + (size_t)(ld * 512 + wave * 64) * 8);
    }
    #pragma unroll
    for (int ld = 0; ld < 4; ++ld) {                 // B: 256 rows x 8 chunks = 2048
        int li  = ld * 512 + tid;
        int row = li >> 3;
        int ch  = (li & 7) ^ (row & 7);
        gload16(B + (size_t)(n0 + row) * 1024 + kt * 64 + ch * 8,
                SMbuf + 8192 + (size_t)(ld * 512 + wave * 64) * 8);
    }
}

__global__ __launch_bounds__(512, 2) void gemm_out(const bf16* __restrict__ A, const bf16* __restrict__ Bw,
                                                   const float* __restrict__ ob, float* __restrict__ out) {
    __shared__ __align__(16) bf16 SM[2 * 24576];   // 96 KB: A 16K + B 32K per buffer
    const int bx = blockIdx.x;
    const int bm = bx >> 2, bn = bx & 3;
    const int m0 = bm * 128, n0 = bn * 256;
    const int tid = threadIdx.x;
    const int lane = tid & 63, wave = tid >> 6;
    const int wm = wave >> 2, wn = wave & 3;       // wave tile: 64 x 64
    const int r16 = lane & 15, c4 = lane >> 4;

    f32x4 acc[4][4];
    #pragma unroll
    for (int i = 0; i < 4; ++i)
        #pragma unroll
        for (int j = 0; j < 4; ++j)
            #pragma unroll
            for (int r = 0; r < 4; ++r) acc[i][j][r] = 0.0f;

    stage_out(A, Bw, m0, n0, 0, SM);
    __syncthreads();
    for (int kt = 0; kt < 16; ++kt) {
        if (kt < 15) stage_out(A, Bw, m0, n0, kt + 1, SM + ((kt + 1) & 1) * 24576);
        const bf16* SMbuf = SM + (kt & 1) * 24576;
        #pragma unroll
        for (int kk = 0; kk < 2; ++kk) {
            bf16x8 bq[4];
            #pragma unroll
            for (int j = 0; j < 4; ++j) {
                int row = wn * 64 + j * 16 + r16;
                int c   = (kk * 4 + c4) ^ (row & 7);
                bq[j] = *(const bf16x8*)(SMbuf + 8192 + row * 64 + c * 8);
            }
            #pragma unroll
            for (int i = 0; i < 4; ++i) {
                int row = wm * 64 + i * 16 + r16;
                int c   = (kk * 4 + c4) ^ (row & 7);
                bf16x8 a = *(const bf16x8*)(SMbuf + row * 64 + c * 8);
                #pragma unroll
                for (int j = 0; j < 4; ++j)
                    acc[i][j] = __builtin_amdgcn_mfma_f32_16x16x32_bf16(a, bq[j], acc[i][j], 0, 0, 0);
            }
        }
        __syncthreads();
    }

    #pragma unroll
    for (int j = 0; j < 4; ++j) {
        int n = n0 + wn * 64 + j * 16 + r16;
        float bias = ob[n];
        #pragma unroll
        for (int i = 0; i < 4; ++i) {
            #pragma unroll
            for (int r = 0; r < 4; ++r) {
                int m = m0 + wm * 64 + i * 16 + c4 * 4 + r;
                if (m < M_) out[(size_t)m * 1024 + n] = acc[i][j][r] + bias;
            }
        }
    }
}

// ---------------- flash attention v8: per-qf softmax->PV interleave, 40 KB LDS ----------------
// R8 structure, but qf0's PV runs before qf1's softmax: ONE per-wave P buffer
// (8 KB total vs 16) -> 40 KB/block -> 4 blocks/CU, and qf1's VALU softmax can
// overlap qf0's MFMA PV cluster. Same-wave LDS write/read to identical address
// expressions keeps program order (must-alias); no cross-wave sharing.
__global__ __launch_bounds__(256) void attn_kernel(const bf16* __restrict__ qk,
                                                   const bf16* __restrict__ vT, bf16* __restrict__ obuf) {
    __shared__ __align__(16) bf16 KV[2][2][4096];      // [buf][K|V][64x64] = 32 KB
    __shared__ __align__(16) char Pls[4 * 2048];       // 8 KB (one P tile per wave)
    const int orig = blockIdx.x;
    const int xcd = orig & 7;
    const int t   = orig >> 3;
    const int qt  = t % 5, bhg = t / 5;
    const int bh  = bhg * 8 + xcd;
    const int b   = bh >> 4, h = bh & 15;
    const int tid = threadIdx.x;
    const int lane = tid & 63, wave = tid >> 6;
    const int r16 = lane & 15, c4 = lane >> 4;
    const int q0  = qt * 128 + wave * 32;
    const int swz = (r16 & 7) << 4;

    const bf16* qp = qk + (size_t)(b * 577) * 2048 + h * 64;
    const bf16* kp = qp + 1024;
    const bf16* vp = vT + (size_t)bh * 64 * SP;

    bf16x8 aq[2][2];
    #pragma unroll
    for (int qf = 0; qf < 2; ++qf)
        #pragma unroll
        for (int c = 0; c < 2; ++c)
            aq[qf][c] = *(const bf16x8*)(qp + (size_t)(q0 + qf * 16 + r16) * 2048 + c * 32 + c4 * 8);

    float mi[2] = {-3.0e38f, -3.0e38f};
    float li[2] = {0.0f, 0.0f};
    f32x4 accO[2][4];
    #pragma unroll
    for (int qf = 0; qf < 2; ++qf)
        #pragma unroll
        for (int nt = 0; nt < 4; ++nt)
            #pragma unroll
            for (int r = 0; r < 4; ++r) accO[qf][nt][r] = 0.0f;

    char* pbase = Pls + wave * 2048 + r16 * 128;

    auto stageKV = [&](int kt, int buf) {
        #pragma unroll
        for (int half = 0; half < 2; ++half) {
            int li  = half * 256 + tid;
            int row = li >> 3;
            int ch  = (li & 7) ^ (row & 7);            // inverse-swizzled source
            bf16* lk = &KV[buf][0][(size_t)(half * 256 + wave * 64) * 8];
            bf16* lv = &KV[buf][1][(size_t)(half * 256 + wave * 64) * 8];
            gload16(kp + (size_t)(kt * 64 + row) * 2048 + ch * 8, lk);
            gload16(vp + (size_t)row * SP + kt * 64 + ch * 8, lv);
        }
    };

    stageKV(0, 0);
    __syncthreads();

    for (int kt = 0; kt < 10; ++kt) {
        const int buf = kt & 1;
        if (kt < 9) stageKV(kt + 1, buf ^ 1);          // async, drained by loop-end barrier

        // ---- K fragments from LDS (swizzled read) + QK^T, both qf ----
        bf16x8 kf[4][2];
        #pragma unroll
        for (int nt = 0; nt < 4; ++nt)
            #pragma unroll
            for (int c = 0; c < 2; ++c) {
                int row = nt * 16 + r16;
                int cc  = (c * 4 + c4) ^ (row & 7);
                kf[nt][c] = *(const bf16x8*)(&KV[buf][0][row * 64 + cc * 8]);
            }
        f32x4 sc[2][4];
        #pragma unroll
        for (int qf = 0; qf < 2; ++qf)
            #pragma unroll
            for (int nt = 0; nt < 4; ++nt) {
                f32x4 z = {0.0f, 0.0f, 0.0f, 0.0f};
                z = __builtin_amdgcn_mfma_f32_16x16x32_bf16(kf[nt][0], aq[qf][0], z, 0, 0, 0);
                sc[qf][nt] = __builtin_amdgcn_mfma_f32_16x16x32_bf16(kf[nt][1], aq[qf][1], z, 0, 0, 0);
            }

        // ---- V fragments once per tile (shared by both qf) ----
        bf16x8 vf[4][2];
        #pragma unroll
        for (int ntd = 0; ntd < 4; ++ntd)
            #pragma unroll
            for (int kk = 0; kk < 2; ++kk) {
                int row = ntd * 16 + r16;
                int cc  = (kk * 4 + c4) ^ (row & 7);
                vf[ntd][kk] = *(const bf16x8*)(&KV[buf][1][row * 64 + cc * 8]);
            }

        // ---- per qf: softmax -> P-LDS -> PV (single P buffer reused) ----
        #pragma unroll
        for (int qf = 0; qf < 2; ++qf) {
            if (kt == 9) {   // only k=576 valid in last tile
                #pragma unroll
                for (int nt = 0; nt < 4; ++nt)
                    #pragma unroll
                    for (int r = 0; r < 4; ++r)
                        if (576 + nt * 16 + c4 * 4 + r >= S_) sc[qf][nt][r] = -3.0e38f;
            }
            float pmax = sc[qf][0][0];
            #pragma unroll
            for (int nt = 0; nt < 4; ++nt)
                #pragma unroll
                for (int r = 0; r < 4; ++r) pmax = fmaxf(pmax, sc[qf][nt][r]);
            pmax = fmaxf(pmax, __shfl_xor(pmax, 16));
            pmax = fmaxf(pmax, __shfl_xor(pmax, 32));

            const bool vrow = (q0 + qf * 16 + r16) < S_;
            int ok = (!vrow) || (pmax <= mi[qf] + 8.0f);
            if (!__all(ok)) {
                float mnew = fmaxf(mi[qf], pmax);
                float fsc  = __builtin_amdgcn_exp2f(mi[qf] - mnew);
                mi[qf] = mnew;
                li[qf] *= fsc;
                float fs0 = __shfl(fsc, c4 * 4 + 0);
                float fs1 = __shfl(fsc, c4 * 4 + 1);
                float fs2 = __shfl(fsc, c4 * 4 + 2);
                float fs3 = __shfl(fsc, c4 * 4 + 3);
                #pragma unroll
                for (int nt = 0; nt < 4; ++nt) {
                    accO[qf][nt][0] *= fs0; accO[qf][nt][1] *= fs1;
                    accO[qf][nt][2] *= fs2; accO[qf][nt][3] *= fs3;
                }
            }
            float p[4][4];
            float rs = 0.0f;
            #pragma unroll
            for (int nt = 0; nt < 4; ++nt)
                #pragma unroll
                for (int r = 0; r < 4; ++r) {
                    p[nt][r] = __builtin_amdgcn_exp2f(sc[qf][nt][r] - mi[qf]);
                    rs += p[nt][r];
                }
            rs += __shfl_xor(rs, 16);
            rs += __shfl_xor(rs, 32);
            li[qf] += rs;
            #pragma unroll
            for (int nt = 0; nt < 4; ++nt) {
                bf16x4 pk;
                pk[0] = (bf16)p[nt][0]; pk[1] = (bf16)p[nt][1];
                pk[2] = (bf16)p[nt][2]; pk[3] = (bf16)p[nt][3];
                *(bf16x4*)(pbase + ((nt * 32 + c4 * 8) ^ swz)) = pk;
            }

            bf16x8 pf[2];
            #pragma unroll
            for (int kk = 0; kk < 2; ++kk)
                pf[kk] = *(const bf16x8*)(pbase + ((kk * 64 + c4 * 16) ^ swz));
            #pragma unroll
            for (int ntd = 0; ntd < 4; ++ntd)
                #pragma unroll
                for (int kk = 0; kk < 2; ++kk)
                    accO[qf][ntd] = __builtin_amdgcn_mfma_f32_16x16x32_bf16(pf[kk], vf[ntd][kk], accO[qf][ntd], 0, 0, 0);
        }

        __syncthreads();   // drains stage(kt+1) + guards buf reuse
    }

    // ---- epilogue ----
    #pragma unroll
    for (int qf = 0; qf < 2; ++qf) {
        float inv = 1.0f / li[qf];
        float rl0 = __shfl(inv, c4 * 4 + 0);
        float rl1 = __shfl(inv, c4 * 4 + 1);
        float rl2 = __shfl(inv, c4 * 4 + 2);
        float rl3 = __shfl(inv, c4 * 4 + 3);
        #pragma unroll
        for (int ntd = 0; ntd < 4; ++ntd) {
            #pragma unroll
            for (int r = 0; r < 4; ++r) {
                int s = q0 + qf * 16 + c4 * 4 + r;
                if (s < S_) {
                    float rl = (r == 0) ? rl0 : (r == 1) ? rl1 : (r == 2) ? rl2 : rl3;
                    obuf[((size_t)(b * S_ + s)) * 1024 + h * 64 + ntd * 16 + r16] =
                        (bf16)(accO[qf][ntd][r] * rl);
                }
            }
        }
    }
}

extern "C" void kernel_launch(void* const* d_in, const int* in_sizes, int n_in,
                              void* d_out, int out_size, void* d_ws, size_t ws_size,
                              hipStream_t stream) {
    const float* hs = (const float*)d_in[0];
    const float* qw = (const float*)d_in[1];
    const float* qb = (const float*)d_in[2];
    const float* kw = (const float*)d_in[3];
    const float* kb = (const float*)d_in[4];
    const float* vw = (const float*)d_in[5];
    const float* vb = (const float*)d_in[6];
    const float* ow = (const float*)d_in[7];
    const float* ob = (const float*)d_in[8];

    char* ws = (char*)d_ws;
    size_t off = 0;
    auto alloc = [&](size_t bytes) { void* p = ws + off; off += (bytes + 255) & ~255UL; return p; };
    bf16* hsA  = (bf16*)alloc((size_t)MP2 * 1024 * 2);   // hidden bf16; reused as attention output
    bf16* wqkv = (bf16*)alloc((size_t)3072 * 1024 * 2);
    bf16* wo   = (bf16*)alloc((size_t)1024 * 1024 * 2);
    bf16* qk   = (bf16*)alloc((size_t)MP2 * 2048 * 2);   // Q cols [0,1024), K cols [1024,2048)
    bf16* vT   = (bf16*)alloc((size_t)BH_ * 64 * SP * 2);

    hipMemsetAsync(vT, 0, (size_t)BH_ * 64 * SP * 2, stream);

    int n4h = M_ * 1024 / 4;
    cast_kernel<<<(n4h + 255) / 256, 256, 0, stream>>>(hs, hsA, n4h);
    cast4_kernel<<<4096, 256, 0, stream>>>(qw, kw, vw, ow,
                                           wqkv, wqkv + 1048576, wqkv + 2097152, wo);

    gemm_qkv<<<73 * 12, 512, 0, stream>>>(hsA, wqkv, qb, kb, vb, qk, vT);
    attn_kernel<<<2560, 256, 0, stream>>>(qk, vT, hsA);
    gemm_out<<<145 * 4, 512, 0, stream>>>(hsA, wo, ob, (float*)d_out);
}